// Round 9
// baseline (276.244 us; speedup 1.0000x reference)
//
#include <hip/hip_runtime.h>
#include <hip/hip_bf16.h>

// QuaternionLinear = one 8192x4096x4096 GEMM vs Hamilton-assembled W.
// Round 9: cross-tile cluster rotation. R8 showed registers (acc128+116=244
// of 256/wave) force the scheduler to sink read-aheads -> LDS reads fully
// exposed (wall 4399 = 2483 MFMA + ~1900 LDS). Defer cluster p3(t) to the
// top of tile t+1: its operands are in regs, so its 16 MFMAs (621 CU-cyc)
// cover the next tile's 12-read LDS burst. No new register cost. Staging
// moved after the mid-barrier (closes the bufA cross-wave race window).

#define M_DIM 8192
#define N_DIM 4096
#define K_DIM 4096
#define BK 64
#define NT (K_DIM / BK)   // 64 K-tiles

typedef __attribute__((ext_vector_type(8))) short bf16x8;
typedef __attribute__((ext_vector_type(4))) float f32x4;
typedef __attribute__((ext_vector_type(8))) unsigned short ushort8;

static __device__ __forceinline__ unsigned short f2bf(float f) {
    unsigned int u = __float_as_uint(f);
    return (unsigned short)((u + 0x7fffu + ((u >> 16) & 1u)) >> 16);
}
static __device__ __forceinline__ unsigned short f2bf_sgn(float f, unsigned int sg) {
    unsigned int u = __float_as_uint(f) ^ sg;
    return (unsigned short)((u + 0x7fffu + ((u >> 16) & 1u)) >> 16);
}

// ---------------- prep: x (fp32) -> xb (bf16) ----------------
__global__ __launch_bounds__(256) void cvt_x_kernel(const float* __restrict__ x,
                                                    unsigned short* __restrict__ xb) {
    int i = (blockIdx.x * 256 + threadIdx.x) * 8;
    f32x4 a = __builtin_nontemporal_load((const f32x4*)(x + i));      // read-once
    f32x4 b = __builtin_nontemporal_load((const f32x4*)(x + i + 4));
    ushort8 o;
    o[0] = f2bf(a[0]); o[1] = f2bf(a[1]); o[2] = f2bf(a[2]); o[3] = f2bf(a[3]);
    o[4] = f2bf(b[0]); o[5] = f2bf(b[1]); o[6] = f2bf(b[2]); o[7] = f2bf(b[3]);
    *(ushort8*)(xb + i) = o;   // xb re-read 16x -> keep cacheable
}

// ---------------- prep: assemble Hamilton W (bf16) ----------------
// Wb[o][i] = sign(p,q) * Wc[p^q][o&1023][i&1023], p=o>>10, q=i>>10,
// neg iff bit (p*4+q) of 0x428E.
__global__ __launch_bounds__(256) void prep_w_kernel(const float* __restrict__ Wr,
    const float* __restrict__ Wi, const float* __restrict__ Wj,
    const float* __restrict__ Wk, unsigned short* __restrict__ wb) {
    int row = blockIdx.x >> 1;
    int col = ((blockIdx.x & 1) * 256 + threadIdx.x) * 8;
    int p = row >> 10, q = col >> 10;
    int ci = p ^ q;
    const float* src = (ci == 0) ? Wr : (ci == 1) ? Wi : (ci == 2) ? Wj : Wk;
    unsigned int sg = ((0x428Eu >> (p * 4 + q)) & 1u) << 31;
    int so = (row & 1023) * 1024 + (col & 1023);
    f32x4 a = *(const f32x4*)(src + so);
    f32x4 b = *(const f32x4*)(src + so + 4);
    ushort8 o;
    o[0] = f2bf_sgn(a[0], sg); o[1] = f2bf_sgn(a[1], sg);
    o[2] = f2bf_sgn(a[2], sg); o[3] = f2bf_sgn(a[3], sg);
    o[4] = f2bf_sgn(b[0], sg); o[5] = f2bf_sgn(b[1], sg);
    o[6] = f2bf_sgn(b[2], sg); o[7] = f2bf_sgn(b[3], sg);
    *(ushort8*)(wb + row * 4096 + col) = o;
}

// ---------------- main GEMM: 256^2, rotated-cluster pipeline ----------------
#define GLD16(gp, lp) __builtin_amdgcn_global_load_lds( \
    (const __attribute__((address_space(1))) void*)(gp), \
    (__attribute__((address_space(3))) void*)(lp), 16, 0, 0)

#define BAR() do { asm volatile("" ::: "memory"); \
                   __builtin_amdgcn_s_barrier(); \
                   asm volatile("" ::: "memory"); } while (0)
#define VM(n) asm volatile("s_waitcnt vmcnt(" #n ")" ::: "memory")

static __device__ __forceinline__ f32x4 MF(bf16x8 a, bf16x8 b, f32x4 c) {
    return __builtin_amdgcn_mfma_f32_16x16x32_bf16(a, b, c, 0, 0, 0);
}

__global__ __launch_bounds__(512, 2) void qgemm_bf16(
    const unsigned short* __restrict__ A, const unsigned short* __restrict__ B,
    const float* __restrict__ bias, float* __restrict__ out)
{
    // [buf][A=0/B=1][half][128 rows][64 shorts] = 128 KiB.
    // Content swizzle: linear 16B slot s at row r holds logical k-slot
    // s^(r&7): pre-swizzled global SOURCE + swizzled ds_read (rule #21).
    __shared__ __align__(16) unsigned short Lsh[2][2][2][128 * 64];

    int bid = blockIdx.x;
    int cpx = gridDim.x >> 3;                 // 512/8 = 64, bijective
    int wg  = (bid & 7) * cpx + (bid >> 3);
    int brow = (wg >> 4) * 256;               // 32 M-tiles
    int bcol = (wg & 15) * 256;               // 16 N-tiles

    int tid   = threadIdx.x;
    int lane  = tid & 63;
    int wid   = tid >> 6;
    int hA    = wid >> 2;                     // wave's A half (128 rows)
    int nb    = wid & 3;                      // wave's 64-col B band
    int hB    = nb >> 1;
    int rB0   = (nb & 1) << 6;
    int fr    = lane & 15;
    int fslot = lane >> 4;                    // 0..3
    unsigned e = (unsigned)(fr & 7);

    const unsigned short* Ag = A + (size_t)brow * K_DIM;
    const unsigned short* Bg = B + (size_t)bcol * K_DIM;
    const char* LshB = (const char*)&Lsh[0][0][0][0];

    // Per-lane read offsets (bytes): base + compile-time imm per fragment.
    // ks=1 = ks=0 ^ 64; buf toggle = ^0x10000.
    unsigned oA0 = (unsigned)hA * 16384u + (unsigned)fr * 128u
                 + ((((unsigned)fslot) ^ e) << 4);
    unsigned oA1 = oA0 ^ 64u;
    unsigned oB0 = 32768u + (unsigned)hB * 16384u
                 + (unsigned)(rB0 + fr) * 128u + ((((unsigned)fslot) ^ e) << 4);
    unsigned oB1 = oB0 ^ 64u;

    f32x4 acc[8][4] = {};

    auto stage = [&](int buf, int ab, int half, int t) {
        const unsigned short* g = (ab ? Bg : Ag) + (size_t)(half << 7) * K_DIM + t * BK;
        unsigned short* l = &Lsh[buf][ab][half][0];
        #pragma unroll
        for (int i = 0; i < 2; ++i) {
            int c = i * 512 + tid;            // 16B chunk: row=c>>3, slot=c&7
            int r = c >> 3, s = c & 7;
            GLD16(g + (size_t)r * K_DIM + ((s ^ (r & 7)) << 3), l + (c << 3));
        }
    };
    auto RD = [&](unsigned off) -> bf16x8 {
        return *(const bf16x8*)(LshB + off);
    };

#define CLUSTER(xa0, xa1, xb0, xb1, ra, rb)                                   \
    do {                                                                      \
        __builtin_amdgcn_s_setprio(1);                                        \
        _Pragma("unroll")                                                     \
        for (int ni = 0; ni < 4; ++ni) acc[ra][ni] = MF(xa0, bf0[ni], acc[ra][ni]); \
        _Pragma("unroll")                                                     \
        for (int ni = 0; ni < 4; ++ni) acc[rb][ni] = MF(xb0, bf0[ni], acc[rb][ni]); \
        _Pragma("unroll")                                                     \
        for (int ni = 0; ni < 4; ++ni) acc[ra][ni] = MF(xa1, bf1[ni], acc[ra][ni]); \
        _Pragma("unroll")                                                     \
        for (int ni = 0; ni < 4; ++ni) acc[rb][ni] = MF(xb1, bf1[ni], acc[rb][ni]); \
        __builtin_amdgcn_s_setprio(0);                                        \
    } while (0)

    bf16x8 bf0[4], bf1[4];                    // B(t) frags, single-buffered
    bf16x8 c3a0, c3a1, c3b0, c3b1;            // carried A pair3 (for rotated p3)

    // Prologue: tile0 A+B into buf0 (8 loads), tile1 B into buf1 (4 loads).
    stage(0, 0, 0, 0); stage(0, 0, 1, 0); stage(0, 1, 0, 0); stage(0, 1, 1, 0);
    stage(1, 1, 0, 1); stage(1, 1, 1, 1);
    VM(4); BAR();

    for (int t = 0; t < NT; ++t) {
        // ---- rotated cluster: p3 of tile t-1 (operands in regs).
        //      Its 16 MFMAs execute while the burst below drains the LDS pipe.
        if (t > 0) CLUSTER(c3a0, c3a1, c3b0, c3b1, 6, 7);

        // ---- read burst for tile t: all B + A pairs 0,1 (WAR on bf regs is
        //      safe: p3's MFMAs issued first, in-order issue per wave) ----
        #pragma unroll
        for (int ni = 0; ni < 4; ++ni) {
            bf0[ni] = RD(oB0 + (unsigned)(ni * 2048));
            bf1[ni] = RD(oB1 + (unsigned)(ni * 2048));
        }
        bf16x8 a0k0 = RD(oA0),          a0k1 = RD(oA1);
        bf16x8 a1k0 = RD(oA0 + 2048u),  a1k1 = RD(oA1 + 2048u);
        bf16x8 a2k0 = RD(oA0 + 4096u),  a2k1 = RD(oA1 + 4096u);
        bf16x8 a3k0 = RD(oA0 + 6144u),  a3k1 = RD(oA1 + 6144u);

        CLUSTER(a0k0, a0k1, a1k0, a1k1, 0, 1);   // p0 (lgkm-waits B + pair0/1)
        BAR();  // all waves' B(t) + A(t-1)-pair3 reads complete -> staging safe

        // ---- staging after barrier: A(t+1) -> bufA^1 (held A(t-1), fully
        //      consumed), B(t+2) -> current buf's B-region (B(t) consumed) ----
        if (t + 1 < NT) { stage((t & 1) ^ 1, 0, 0, t + 1); stage((t & 1) ^ 1, 0, 1, t + 1); }
        if (t + 2 < NT) { stage(t & 1, 1, 0, t + 2); stage(t & 1, 1, 1, t + 2); }

        bf16x8 a4k0 = RD(oA0 + 8192u),  a4k1 = RD(oA1 + 8192u);
        bf16x8 a5k0 = RD(oA0 + 10240u), a5k1 = RD(oA1 + 10240u);
        CLUSTER(a2k0, a2k1, a3k0, a3k1, 2, 3);   // p1

        c3a0 = RD(oA0 + 12288u); c3a1 = RD(oA1 + 12288u);   // pair3 read-ahead
        c3b0 = RD(oA0 + 14336u); c3b1 = RD(oA1 + 14336u);   // (consumed next tile)
        CLUSTER(a4k0, a4k1, a5k0, a5k1, 4, 5);   // p2

        // Retire A(t+1)+B(t+1); leave the 4 newest (B(t+2)) in flight.
        if (t < NT - 2) { VM(4); } else { VM(0); }
        BAR();
        oA0 ^= 0x10000u; oA1 ^= 0x10000u; oB0 ^= 0x10000u; oB1 ^= 0x10000u;
    }
    // final rotated cluster: p3 of tile NT-1
    CLUSTER(c3a0, c3a1, c3b0, c3b1, 6, 7);
#undef CLUSTER

    // epilogue: C/D layout col=lane&15, row=(lane>>4)*4+reg.
    int cr = (lane >> 4) << 2;
    int cc = lane & 15;
    #pragma unroll
    for (int ni = 0; ni < 4; ++ni) {
        int col = bcol + nb * 64 + ni * 16 + cc;
        float bv = bias[col];
        #pragma unroll
        for (int mi = 0; mi < 8; ++mi) {
            int r0 = brow + hA * 128 + mi * 16 + cr;
            #pragma unroll
            for (int r = 0; r < 4; ++r)
                __builtin_nontemporal_store(acc[mi][ni][r] + bv,
                                            &out[(size_t)(r0 + r) * N_DIM + col]);
        }
    }
}

// ---------------- fallback: reg-staged, no workspace (round-3, known-good) --
#define FBM 128
#define FBN 128
#define FBK 64
__global__ __launch_bounds__(256) void qgemm_fb(const float* __restrict__ x,
    const float* __restrict__ Wr, const float* __restrict__ Wi,
    const float* __restrict__ Wj, const float* __restrict__ Wk,
    const float* __restrict__ bias, float* __restrict__ out)
{
    __shared__ unsigned short As[FBM * FBK];
    __shared__ unsigned short Bs[FBN * FBK];

    int bid = blockIdx.x;
    int cpx = gridDim.x >> 3;
    int wg = (bid & 7) * cpx + (bid >> 3);
    int brow = (wg >> 5) * FBM;
    int bcol = (wg & 31) * FBN;

    int tid = threadIdx.x;
    int lane = tid & 63;
    int wv = tid >> 6;
    int wm = (wv >> 1) << 6;
    int wn = (wv & 1) << 6;
    int fr = lane & 15;
    int fk = (lane >> 4) << 3;

    int p = bcol >> 10;
    f32x4 acc[4][4] = {};

    for (int kt = 0; kt < K_DIM / FBK; ++kt) {
        int k0 = kt * FBK;
        int q = k0 >> 10;
        int ci = p ^ q;
        const float* wsrc = (ci == 0) ? Wr : (ci == 1) ? Wi : (ci == 2) ? Wj : Wk;
        unsigned int sg = ((0x428Eu >> (p * 4 + q)) & 1u) << 31;

        __syncthreads();
        #pragma unroll
        for (int i = 0; i < 4; ++i) {
            int c = i * 256 + tid;
            int row = c >> 3, colo = (c & 7) << 3;
            const float* s = x + (size_t)(brow + row) * K_DIM + k0 + colo;
            float4 a = *(const float4*)s;
            float4 b = *(const float4*)(s + 4);
            ushort8 o;
            o[0] = f2bf(a.x); o[1] = f2bf(a.y); o[2] = f2bf(a.z); o[3] = f2bf(a.w);
            o[4] = f2bf(b.x); o[5] = f2bf(b.y); o[6] = f2bf(b.z); o[7] = f2bf(b.w);
            *(ushort8*)(&As[c << 3]) = o;
        }
        #pragma unroll
        for (int i = 0; i < 4; ++i) {
            int c = i * 256 + tid;
            int row = c >> 3, colo = (c & 7) << 3;
            const float* s = wsrc + ((bcol + row) & 1023) * 1024 + ((k0 + colo) & 1023);
            float4 a = *(const float4*)s;
            float4 b = *(const float4*)(s + 4);
            ushort8 o;
            o[0] = f2bf_sgn(a.x, sg); o[1] = f2bf_sgn(a.y, sg);
            o[2] = f2bf_sgn(a.z, sg); o[3] = f2bf_sgn(a.w, sg);
            o[4] = f2bf_sgn(b.x, sg); o[5] = f2bf_sgn(b.y, sg);
            o[6] = f2bf_sgn(b.z, sg); o[7] = f2bf_sgn(b.w, sg);
            *(ushort8*)(&Bs[c << 3]) = o;
        }
        __syncthreads();

        #pragma unroll
        for (int ks = 0; ks < 2; ++ks) {
            bf16x8 af[4], bfr[4];
            #pragma unroll
            for (int m = 0; m < 4; ++m)
                af[m] = *(const bf16x8*)(&As[(wm + m * 16 + fr) * FBK + ks * 32 + fk]);
            #pragma unroll
            for (int n = 0; n < 4; ++n)
                bfr[n] = *(const bf16x8*)(&Bs[(wn + n * 16 + fr) * FBK + ks * 32 + fk]);
            #pragma unroll
            for (int m = 0; m < 4; ++m)
                #pragma unroll
                for (int n = 0; n < 4; ++n)
                    acc[m][n] = __builtin_amdgcn_mfma_f32_16x16x32_bf16(
                        af[m], bfr[n], acc[m][n], 0, 0, 0);
        }
    }

    int cr = (lane >> 4) << 2;
    int cc = lane & 15;
    #pragma unroll
    for (int n = 0; n < 4; ++n) {
        int col = bcol + wn + n * 16 + cc;
        float bv = bias[col];
        #pragma unroll
        for (int m = 0; m < 4; ++m) {
            int r0 = brow + wm + m * 16 + cr;
            #pragma unroll
            for (int r = 0; r < 4; ++r)
                out[(size_t)(r0 + r) * N_DIM + col] = acc[m][n][r] + bv;
        }
    }
}

extern "C" void kernel_launch(void* const* d_in, const int* in_sizes, int n_in,
                              void* d_out, int out_size, void* d_ws, size_t ws_size,
                              hipStream_t stream) {
    const float* x    = (const float*)d_in[0];
    const float* Wr   = (const float*)d_in[1];
    const float* Wi   = (const float*)d_in[2];
    const float* Wj   = (const float*)d_in[3];
    const float* Wk   = (const float*)d_in[4];
    const float* bias = (const float*)d_in[5];
    float* out = (float*)d_out;

    const size_t xb_bytes = (size_t)M_DIM * K_DIM * 2;  // 64 MiB
    const size_t wb_bytes = (size_t)N_DIM * K_DIM * 2;  // 32 MiB

    if (ws_size >= xb_bytes + wb_bytes) {
        unsigned short* xb = (unsigned short*)d_ws;
        unsigned short* wb = (unsigned short*)((char*)d_ws + xb_bytes);
        cvt_x_kernel<<<(M_DIM * K_DIM) / 2048, 256, 0, stream>>>(x, xb);
        prep_w_kernel<<<N_DIM * 2, 256, 0, stream>>>(Wr, Wi, Wj, Wk, wb);
        const int n_blocks = (M_DIM / 256) * (N_DIM / 256);  // 512
        qgemm_bf16<<<n_blocks, 512, 0, stream>>>(xb, wb, bias, out);
    } else {
        const int n_blocks = (M_DIM / FBM) * (N_DIM / FBN);  // 2048
        qgemm_fb<<<n_blocks, 256, 0, stream>>>(x, Wr, Wi, Wj, Wk, bias, out);
    }
}

// Round 10
// 274.371 us; speedup vs baseline: 1.0068x; 1.0068x over previous
//
#include <hip/hip_runtime.h>
#include <hip/hip_bf16.h>

// QuaternionLinear = one 8192x4096x4096 GEMM vs Hamilton-assembled W.
// Round 10: occupancy axis. R7-R9 (intra-wave scheduling) all plateaued at
// ~52% MfmaUtil: 128KiB LDS -> 1 block/CU -> 2 waves/SIMD in lockstep, and
// acc(128)+116 VGPR leaves no room for read-ahead ILP. Restructure: same
// 256^2 tile / BK=64 / 128KiB LDS, but 16 waves (1024 thr), wave tile 64x64
// (acc 64 VGPR), __launch_bounds__(1024,4) -> 4 waves/SIMD. LDS-read latency
// now hidden by TLP (other waves' MFMA clusters), not ILP.

#define M_DIM 8192
#define N_DIM 4096
#define K_DIM 4096
#define BK 64
#define NT (K_DIM / BK)   // 64 K-tiles

typedef __attribute__((ext_vector_type(8))) short bf16x8;
typedef __attribute__((ext_vector_type(4))) float f32x4;
typedef __attribute__((ext_vector_type(8))) unsigned short ushort8;

static __device__ __forceinline__ unsigned short f2bf(float f) {
    unsigned int u = __float_as_uint(f);
    return (unsigned short)((u + 0x7fffu + ((u >> 16) & 1u)) >> 16);
}
static __device__ __forceinline__ unsigned short f2bf_sgn(float f, unsigned int sg) {
    unsigned int u = __float_as_uint(f) ^ sg;
    return (unsigned short)((u + 0x7fffu + ((u >> 16) & 1u)) >> 16);
}

// ---------------- prep: x (fp32) -> xb (bf16) ----------------
__global__ __launch_bounds__(256) void cvt_x_kernel(const float* __restrict__ x,
                                                    unsigned short* __restrict__ xb) {
    int i = (blockIdx.x * 256 + threadIdx.x) * 8;
    f32x4 a = __builtin_nontemporal_load((const f32x4*)(x + i));      // read-once
    f32x4 b = __builtin_nontemporal_load((const f32x4*)(x + i + 4));
    ushort8 o;
    o[0] = f2bf(a[0]); o[1] = f2bf(a[1]); o[2] = f2bf(a[2]); o[3] = f2bf(a[3]);
    o[4] = f2bf(b[0]); o[5] = f2bf(b[1]); o[6] = f2bf(b[2]); o[7] = f2bf(b[3]);
    *(ushort8*)(xb + i) = o;   // xb re-read 16x -> keep cacheable
}

// ---------------- prep: assemble Hamilton W (bf16) ----------------
// Wb[o][i] = sign(p,q) * Wc[p^q][o&1023][i&1023], p=o>>10, q=i>>10,
// neg iff bit (p*4+q) of 0x428E.
__global__ __launch_bounds__(256) void prep_w_kernel(const float* __restrict__ Wr,
    const float* __restrict__ Wi, const float* __restrict__ Wj,
    const float* __restrict__ Wk, unsigned short* __restrict__ wb) {
    int row = blockIdx.x >> 1;
    int col = ((blockIdx.x & 1) * 256 + threadIdx.x) * 8;
    int p = row >> 10, q = col >> 10;
    int ci = p ^ q;
    const float* src = (ci == 0) ? Wr : (ci == 1) ? Wi : (ci == 2) ? Wj : Wk;
    unsigned int sg = ((0x428Eu >> (p * 4 + q)) & 1u) << 31;
    int so = (row & 1023) * 1024 + (col & 1023);
    f32x4 a = *(const f32x4*)(src + so);
    f32x4 b = *(const f32x4*)(src + so + 4);
    ushort8 o;
    o[0] = f2bf_sgn(a[0], sg); o[1] = f2bf_sgn(a[1], sg);
    o[2] = f2bf_sgn(a[2], sg); o[3] = f2bf_sgn(a[3], sg);
    o[4] = f2bf_sgn(b[0], sg); o[5] = f2bf_sgn(b[1], sg);
    o[6] = f2bf_sgn(b[2], sg); o[7] = f2bf_sgn(b[3], sg);
    *(ushort8*)(wb + row * 4096 + col) = o;
}

// ---------------- main GEMM: 256^2, 16 waves, 2-barrier window ----------------
#define GLD16(gp, lp) __builtin_amdgcn_global_load_lds( \
    (const __attribute__((address_space(1))) void*)(gp), \
    (__attribute__((address_space(3))) void*)(lp), 16, 0, 0)

#define BAR() do { asm volatile("" ::: "memory"); \
                   __builtin_amdgcn_s_barrier(); \
                   asm volatile("" ::: "memory"); } while (0)
#define VM(n) asm volatile("s_waitcnt vmcnt(" #n ")" ::: "memory")

static __device__ __forceinline__ f32x4 MF(bf16x8 a, bf16x8 b, f32x4 c) {
    return __builtin_amdgcn_mfma_f32_16x16x32_bf16(a, b, c, 0, 0, 0);
}

__global__ __launch_bounds__(1024, 4) void qgemm_bf16(
    const unsigned short* __restrict__ A, const unsigned short* __restrict__ B,
    const float* __restrict__ bias, float* __restrict__ out)
{
    // [buf][A=0/B=1][256 rows][64 shorts] = 128 KiB.
    // Content swizzle: linear 16B slot s at row r holds logical k-slot
    // s^(r&7): pre-swizzled global SOURCE + swizzled ds_read (rule #21).
    // buf toggle = byte ^0x10000; B-region = +0x8000.
    __shared__ __align__(16) unsigned short Lsh[2][2][256 * 64];

    int bid = blockIdx.x;
    int cpx = gridDim.x >> 3;                 // 512/8 = 64, bijective
    int wg  = (bid & 7) * cpx + (bid >> 3);
    int brow = (wg >> 4) * 256;               // 32 M-tiles
    int bcol = (wg & 15) * 256;               // 16 N-tiles

    int tid   = threadIdx.x;
    int lane  = tid & 63;
    int wid   = tid >> 6;                     // 0..15
    int wm    = wid >> 2;                     // wave row-band (64 rows)
    int wn    = wid & 3;                      // wave col-band (64 cols)
    int fr    = lane & 15;
    int fslot = lane >> 4;                    // 0..3
    unsigned e = (unsigned)(fr & 7);

    const unsigned short* Ag = A + (size_t)brow * K_DIM;
    const unsigned short* Bg = B + (size_t)bcol * K_DIM;
    const char* LshB = (const char*)&Lsh[0][0][0];

    // Per-lane read bases (bytes); fragment = base + compile-time imm.
    // mi/ni stride 2048; ks=1 = ^64 (slot^4); buf = ^0x10000.
    unsigned oA0 = (unsigned)wm * 8192u + (unsigned)fr * 128u
                 + ((((unsigned)fslot) ^ e) << 4);
    unsigned oA1 = oA0 ^ 64u;
    unsigned oB0 = 0x8000u + (unsigned)wn * 8192u + (unsigned)fr * 128u
                 + ((((unsigned)fslot) ^ e) << 4);
    unsigned oB1 = oB0 ^ 64u;

    f32x4 acc[4][4] = {};

    // stage one full 256x64 matrix tile (32 KB) = 2 x 1024-thread GLD16.
    auto stage = [&](int buf, int ab, int t) {
        const unsigned short* g = (ab ? Bg : Ag) + t * BK;
        unsigned short* l = &Lsh[buf][ab][0];
        #pragma unroll
        for (int i = 0; i < 2; ++i) {
            int c = i * 1024 + tid;           // 16B chunk: row=c>>3, slot=c&7
            int r = c >> 3, s = c & 7;
            GLD16(g + (size_t)r * K_DIM + ((s ^ (r & 7)) << 3), l + (c << 3));
        }
    };
    auto RD = [&](unsigned off) -> bf16x8 {
        return *(const bf16x8*)(LshB + off);
    };

    // mi-cluster: read A pair (8 VGPR), 8 MFMA. Per-wave serialization is
    // hidden by 4 waves/SIMD (TLP), not ILP.
#define CLUSTER(mi)                                                           \
    do {                                                                      \
        bf16x8 a0 = RD(oA0 + (mi) * 2048u), a1 = RD(oA1 + (mi) * 2048u);      \
        __builtin_amdgcn_s_setprio(1);                                        \
        _Pragma("unroll")                                                     \
        for (int ni = 0; ni < 4; ++ni) acc[mi][ni] = MF(a0, bf0[ni], acc[mi][ni]); \
        _Pragma("unroll")                                                     \
        for (int ni = 0; ni < 4; ++ni) acc[mi][ni] = MF(a1, bf1[ni], acc[mi][ni]); \
        __builtin_amdgcn_s_setprio(0);                                        \
    } while (0)

    bf16x8 bf0[4], bf1[4];                    // B(t) frags (32 VGPR)

    // Prologue: A(0),B(0) -> buf0; B(1) -> buf1. VM(2) retires A(0),B(0).
    stage(0, 0, 0); stage(0, 1, 0); stage(1, 1, 1);
    VM(2); BAR();

    for (int t = 0; t < NT; ++t) {
        int buf = t & 1;

        // ---- stage A(t+1) -> other buf's A-region (dead: A(t-1) fully
        //      consumed last tile); read all B(t) frags + cluster mi0 ----
        if (t + 1 < NT) stage(buf ^ 1, 0, t + 1);
        #pragma unroll
        for (int ni = 0; ni < 4; ++ni) {
            bf0[ni] = RD(oB0 + (unsigned)(ni * 2048));
            bf1[ni] = RD(oB1 + (unsigned)(ni * 2048));
        }
        CLUSTER(0);   // consumes all B reads -> lgkm retired before BAR
        BAR();        // all waves done reading B-region -> safe to overwrite

        // ---- stage B(t+2) into current buf's B-region; clusters mi1..mi3 ----
        if (t + 2 < NT) stage(buf, 1, t + 2);
        CLUSTER(1);
        CLUSTER(2);
        CLUSTER(3);

        // Outstanding (issue order): B(t+1)x2, A(t+1)x2, B(t+2)x2.
        // VM(2) retires B(t+1)+A(t+1), leaves B(t+2) in flight.
        if (t < NT - 2) { VM(2); } else { VM(0); }
        BAR();
        oA0 ^= 0x10000u; oA1 ^= 0x10000u; oB0 ^= 0x10000u; oB1 ^= 0x10000u;
    }
#undef CLUSTER

    // epilogue: C/D layout col=lane&15, row=(lane>>4)*4+reg.
    int cr = (lane >> 4) << 2;
    int cc = lane & 15;
    #pragma unroll
    for (int ni = 0; ni < 4; ++ni) {
        int col = bcol + wn * 64 + ni * 16 + cc;
        float bv = bias[col];
        #pragma unroll
        for (int mi = 0; mi < 4; ++mi) {
            int r0 = brow + wm * 64 + mi * 16 + cr;
            #pragma unroll
            for (int r = 0; r < 4; ++r)
                __builtin_nontemporal_store(acc[mi][ni][r] + bv,
                                            &out[(size_t)(r0 + r) * N_DIM + col]);
        }
    }
}

// ---------------- fallback: reg-staged, no workspace (round-3, known-good) --
#define FBM 128
#define FBN 128
#define FBK 64
__global__ __launch_bounds__(256) void qgemm_fb(const float* __restrict__ x,
    const float* __restrict__ Wr, const float* __restrict__ Wi,
    const float* __restrict__ Wj, const float* __restrict__ Wk,
    const float* __restrict__ bias, float* __restrict__ out)
{
    __shared__ unsigned short As[FBM * FBK];
    __shared__ unsigned short Bs[FBN * FBK];

    int bid = blockIdx.x;
    int cpx = gridDim.x >> 3;
    int wg = (bid & 7) * cpx + (bid >> 3);
    int brow = (wg >> 5) * FBM;
    int bcol = (wg & 31) * FBN;

    int tid = threadIdx.x;
    int lane = tid & 63;
    int wv = tid >> 6;
    int wm = (wv >> 1) << 6;
    int wn = (wv & 1) << 6;
    int fr = lane & 15;
    int fk = (lane >> 4) << 3;

    int p = bcol >> 10;
    f32x4 acc[4][4] = {};

    for (int kt = 0; kt < K_DIM / FBK; ++kt) {
        int k0 = kt * FBK;
        int q = k0 >> 10;
        int ci = p ^ q;
        const float* wsrc = (ci == 0) ? Wr : (ci == 1) ? Wi : (ci == 2) ? Wj : Wk;
        unsigned int sg = ((0x428Eu >> (p * 4 + q)) & 1u) << 31;

        __syncthreads();
        #pragma unroll
        for (int i = 0; i < 4; ++i) {
            int c = i * 256 + tid;
            int row = c >> 3, colo = (c & 7) << 3;
            const float* s = x + (size_t)(brow + row) * K_DIM + k0 + colo;
            float4 a = *(const float4*)s;
            float4 b = *(const float4*)(s + 4);
            ushort8 o;
            o[0] = f2bf(a.x); o[1] = f2bf(a.y); o[2] = f2bf(a.z); o[3] = f2bf(a.w);
            o[4] = f2bf(b.x); o[5] = f2bf(b.y); o[6] = f2bf(b.z); o[7] = f2bf(b.w);
            *(ushort8*)(&As[c << 3]) = o;
        }
        #pragma unroll
        for (int i = 0; i < 4; ++i) {
            int c = i * 256 + tid;
            int row = c >> 3, colo = (c & 7) << 3;
            const float* s = wsrc + ((bcol + row) & 1023) * 1024 + ((k0 + colo) & 1023);
            float4 a = *(const float4*)s;
            float4 b = *(const float4*)(s + 4);
            ushort8 o;
            o[0] = f2bf_sgn(a.x, sg); o[1] = f2bf_sgn(a.y, sg);
            o[2] = f2bf_sgn(a.z, sg); o[3] = f2bf_sgn(a.w, sg);
            o[4] = f2bf_sgn(b.x, sg); o[5] = f2bf_sgn(b.y, sg);
            o[6] = f2bf_sgn(b.z, sg); o[7] = f2bf_sgn(b.w, sg);
            *(ushort8*)(&Bs[c << 3]) = o;
        }
        __syncthreads();

        #pragma unroll
        for (int ks = 0; ks < 2; ++ks) {
            bf16x8 af[4], bfr[4];
            #pragma unroll
            for (int m = 0; m < 4; ++m)
                af[m] = *(const bf16x8*)(&As[(wm + m * 16 + fr) * FBK + ks * 32 + fk]);
            #pragma unroll
            for (int n = 0; n < 4; ++n)
                bfr[n] = *(const bf16x8*)(&Bs[(wn + n * 16 + fr) * FBK + ks * 32 + fk]);
            #pragma unroll
            for (int m = 0; m < 4; ++m)
                #pragma unroll
                for (int n = 0; n < 4; ++n)
                    acc[m][n] = __builtin_amdgcn_mfma_f32_16x16x32_bf16(
                        af[m], bfr[n], acc[m][n], 0, 0, 0);
        }
    }

    int cr = (lane >> 4) << 2;
    int cc = lane & 15;
    #pragma unroll
    for (int n = 0; n < 4; ++n) {
        int col = bcol + wn + n * 16 + cc;
        float bv = bias[col];
        #pragma unroll
        for (int m = 0; m < 4; ++m) {
            int r0 = brow + wm + m * 16 + cr;
            #pragma unroll
            for (int r = 0; r < 4; ++r)
                out[(size_t)(r0 + r) * N_DIM + col] = acc[m][n][r] + bv;
        }
    }
}

extern "C" void kernel_launch(void* const* d_in, const int* in_sizes, int n_in,
                              void* d_out, int out_size, void* d_ws, size_t ws_size,
                              hipStream_t stream) {
    const float* x    = (const float*)d_in[0];
    const float* Wr   = (const float*)d_in[1];
    const float* Wi   = (const float*)d_in[2];
    const float* Wj   = (const float*)d_in[3];
    const float* Wk   = (const float*)d_in[4];
    const float* bias = (const float*)d_in[5];
    float* out = (float*)d_out;

    const size_t xb_bytes = (size_t)M_DIM * K_DIM * 2;  // 64 MiB
    const size_t wb_bytes = (size_t)N_DIM * K_DIM * 2;  // 32 MiB

    if (ws_size >= xb_bytes + wb_bytes) {
        unsigned short* xb = (unsigned short*)d_ws;
        unsigned short* wb = (unsigned short*)((char*)d_ws + xb_bytes);
        cvt_x_kernel<<<(M_DIM * K_DIM) / 2048, 256, 0, stream>>>(x, xb);
        prep_w_kernel<<<N_DIM * 2, 256, 0, stream>>>(Wr, Wi, Wj, Wk, wb);
        const int n_blocks = (M_DIM / 256) * (N_DIM / 256);  // 512
        qgemm_bf16<<<n_blocks, 1024, 0, stream>>>(xb, wb, bias, out);
    } else {
        const int n_blocks = (M_DIM / FBM) * (N_DIM / FBN);  // 2048
        qgemm_fb<<<n_blocks, 256, 0, stream>>>(x, Wr, Wi, Wj, Wk, bias, out);
    }
}